// Round 1
// baseline (231.977 us; speedup 1.0000x reference)
//
#include <hip/hip_runtime.h>

typedef _Float16 f16;
typedef _Float16 f16x8 __attribute__((ext_vector_type(8)));
typedef float f32x4 __attribute__((ext_vector_type(4)));

#define NTOK 4096
#define CIN  256
#define C3   768
#define CO   256
#define NH   8
#define DH   32

__device__ __forceinline__ f32x4 mfma16(f16x8 a, f16x8 b, f32x4 c) {
  return __builtin_amdgcn_mfma_f32_16x16x32_f16(a, b, c, 0, 0, 0);
}

// ---------------------------------------------------------------------------
// Kernel 1: qkv = x^T @ W_qkv + b_qkv  (x is [B, C, N] channel-major)
// Writes: qbuf [bh][n][32] f16, PRE-SCALED by 1/sqrt(32)
//         kbuf [bh][n][32] f16
//         vbuf [bh][d][n]  f16 (d-major so attention can stage V^T w/ vector copies)
// ---------------------------------------------------------------------------
__global__ __launch_bounds__(256) void qkv_kernel(
    const float* __restrict__ x, const float* __restrict__ Wqkv,
    const float* __restrict__ bqkv,
    f16* __restrict__ qbuf, f16* __restrict__ kbuf, f16* __restrict__ vbuf)
{
  __shared__ f16 As[64][40];   // [n][c] transposed x tile
  __shared__ f16 Bs[64][40];   // [j][c] transposed W tile
  const int b  = blockIdx.z;
  const int n0 = blockIdx.x * 64;
  const int j0 = blockIdx.y * 64;
  const int t  = threadIdx.x;
  const int w  = t >> 6;
  const int lane = t & 63;
  const int l16  = lane & 15;
  const int g4   = lane >> 4;
  const int cl = t >> 3;        // 0..31
  const int el = (t & 7) * 8;   // 0..56

  f32x4 acc[4] = {};
  for (int k0 = 0; k0 < CIN; k0 += 32) {
    const float* xp = x + ((size_t)b * CIN + (k0 + cl)) * NTOK + n0 + el;
    float4 a0 = *reinterpret_cast<const float4*>(xp);
    float4 a1 = *reinterpret_cast<const float4*>(xp + 4);
    const float* wp = Wqkv + (size_t)(k0 + cl) * C3 + j0 + el;
    float4 b0 = *reinterpret_cast<const float4*>(wp);
    float4 b1 = *reinterpret_cast<const float4*>(wp + 4);
    As[el + 0][cl] = (f16)a0.x;  As[el + 1][cl] = (f16)a0.y;
    As[el + 2][cl] = (f16)a0.z;  As[el + 3][cl] = (f16)a0.w;
    As[el + 4][cl] = (f16)a1.x;  As[el + 5][cl] = (f16)a1.y;
    As[el + 6][cl] = (f16)a1.z;  As[el + 7][cl] = (f16)a1.w;
    Bs[el + 0][cl] = (f16)b0.x;  Bs[el + 1][cl] = (f16)b0.y;
    Bs[el + 2][cl] = (f16)b0.z;  Bs[el + 3][cl] = (f16)b0.w;
    Bs[el + 4][cl] = (f16)b1.x;  Bs[el + 5][cl] = (f16)b1.y;
    Bs[el + 6][cl] = (f16)b1.z;  Bs[el + 7][cl] = (f16)b1.w;
    __syncthreads();
    f16x8 bf = *reinterpret_cast<const f16x8*>(&Bs[w * 16 + l16][g4 * 8]);
#pragma unroll
    for (int mf = 0; mf < 4; ++mf) {
      f16x8 af = *reinterpret_cast<const f16x8*>(&As[mf * 16 + l16][g4 * 8]);
      acc[mf] = mfma16(af, bf, acc[mf]);
    }
    __syncthreads();
  }
  const int j  = j0 + w * 16 + l16;
  const int s  = j >> 8;           // 0=q 1=k 2=v
  const int hh = (j >> 5) & 7;
  const int d  = j & 31;
  const float bias = bqkv[j];
  const float qscale = 0.17677669529663687f;  // 1/sqrt(32)
#pragma unroll
  for (int mf = 0; mf < 4; ++mf) {
#pragma unroll
    for (int r = 0; r < 4; ++r) {
      const int n = n0 + mf * 16 + g4 * 4 + r;
      const float v = acc[mf][r] + bias;
      if (s == 0) {
        qbuf[(((size_t)b * NH + hh) * NTOK + n) * DH + d] = (f16)(v * qscale);
      } else if (s == 1) {
        kbuf[(((size_t)b * NH + hh) * NTOK + n) * DH + d] = (f16)v;
      } else {
        vbuf[(((size_t)(b * NH + hh)) * DH + d) * NTOK + n] = (f16)v;
      }
    }
  }
}

// ---------------------------------------------------------------------------
// Kernel 2: flash attention. One block = 64 query rows of one (b,h).
// 4 waves, each owns 16 query rows. KV tiles of 64 staged in LDS.
// ---------------------------------------------------------------------------
__global__ __launch_bounds__(256) void attn_kernel(
    const f16* __restrict__ qbuf, const f16* __restrict__ kbuf,
    const f16* __restrict__ vbuf, f16* __restrict__ ao)
{
  __shared__ f16 Ks[64][40];       // [kv][c]
  __shared__ f16 Vt[32][72];       // [d][kv]
  __shared__ f16 Ps[4][16][72];    // per-wave [m][kv]
  const int bh = blockIdx.y;
  const int b = bh >> 3, h = bh & 7;
  const int q0 = blockIdx.x * 64;
  const int t = threadIdx.x, w = t >> 6, lane = t & 63;
  const int l16 = lane & 15, g4 = lane >> 4;
  const size_t kbase = (size_t)bh * NTOK * DH;
  f16x8 qfrag = *reinterpret_cast<const f16x8*>(
      qbuf + kbase + (size_t)(q0 + w * 16 + l16) * DH + g4 * 8);
  f32x4 oacc[2] = {};
  float mrun[4], lrun[4];
#pragma unroll
  for (int r = 0; r < 4; ++r) { mrun[r] = -1e30f; lrun[r] = 0.f; }
  const int krow = t >> 2, koff = (t & 3) * 8;   // K stage: 64 rows x 32
  const int vd = t >> 3, vkoff = (t & 7) * 8;    // V stage: 32 rows x 64

  for (int kv0 = 0; kv0 < NTOK; kv0 += 64) {
    f16x8 kk = *reinterpret_cast<const f16x8*>(
        kbuf + kbase + (size_t)(kv0 + krow) * DH + koff);
    f16x8 vv = *reinterpret_cast<const f16x8*>(
        vbuf + kbase + (size_t)vd * NTOK + kv0 + vkoff);
    *reinterpret_cast<f16x8*>(&Ks[krow][koff]) = kk;
    *reinterpret_cast<f16x8*>(&Vt[vd][vkoff]) = vv;
    __syncthreads();
    // S = Q K^T  (Q pre-scaled)
    f32x4 sv[4];
#pragma unroll
    for (int nf = 0; nf < 4; ++nf) {
      f16x8 kf = *reinterpret_cast<const f16x8*>(&Ks[nf * 16 + l16][g4 * 8]);
      f32x4 z = {};
      sv[nf] = mfma16(qfrag, kf, z);
    }
    // online softmax; row r of this 16-lane group = q-row g4*4+r
#pragma unroll
    for (int r = 0; r < 4; ++r) {
      float mx = fmaxf(fmaxf(sv[0][r], sv[1][r]), fmaxf(sv[2][r], sv[3][r]));
      mx = fmaxf(mx, __shfl_xor(mx, 1));
      mx = fmaxf(mx, __shfl_xor(mx, 2));
      mx = fmaxf(mx, __shfl_xor(mx, 4));
      mx = fmaxf(mx, __shfl_xor(mx, 8));
      const float mnew = fmaxf(mrun[r], mx);
      const float alpha = __expf(mrun[r] - mnew);
      mrun[r] = mnew;
      float lsum = 0.f;
#pragma unroll
      for (int nf = 0; nf < 4; ++nf) {
        const float p = __expf(sv[nf][r] - mnew);
        sv[nf][r] = p;
        lsum += p;
      }
      lsum += __shfl_xor(lsum, 1);
      lsum += __shfl_xor(lsum, 2);
      lsum += __shfl_xor(lsum, 4);
      lsum += __shfl_xor(lsum, 8);
      lrun[r] = lrun[r] * alpha + lsum;
      oacc[0][r] *= alpha;
      oacc[1][r] *= alpha;
    }
    // P -> LDS (D-layout -> A-fragment layout round trip)
#pragma unroll
    for (int nf = 0; nf < 4; ++nf)
#pragma unroll
      for (int r = 0; r < 4; ++r)
        Ps[w][g4 * 4 + r][nf * 16 + l16] = (f16)sv[nf][r];
    // O += P V
#pragma unroll
    for (int ks = 0; ks < 2; ++ks) {
      f16x8 pa = *reinterpret_cast<const f16x8*>(&Ps[w][l16][ks * 32 + g4 * 8]);
#pragma unroll
      for (int df = 0; df < 2; ++df) {
        f16x8 vb = *reinterpret_cast<const f16x8*>(&Vt[df * 16 + l16][ks * 32 + g4 * 8]);
        oacc[df] = mfma16(pa, vb, oacc[df]);
      }
    }
    __syncthreads();
  }
#pragma unroll
  for (int df = 0; df < 2; ++df)
#pragma unroll
    for (int r = 0; r < 4; ++r) {
      const int n = q0 + w * 16 + g4 * 4 + r;
      const int c = h * DH + df * 16 + l16;
      ao[((size_t)b * NTOK + n) * CO + c] = (f16)(oacc[df][r] / lrun[r]);
    }
}

// ---------------------------------------------------------------------------
// Kernel 3: out[b][j][n] = sum_c ao[b][n][c] * Wout[c][j] + bout[j]
// A-operand = W^T (m=j), B-operand = ao (n-col = token) -> direct transposed store
// ---------------------------------------------------------------------------
__global__ __launch_bounds__(256) void proj_kernel(
    const f16* __restrict__ ao, const float* __restrict__ Wout,
    const float* __restrict__ bout, float* __restrict__ out)
{
  __shared__ f16 Ws[64][40];    // [j][c]
  __shared__ f16 Aos[64][40];   // [n][c]
  const int b  = blockIdx.z;
  const int n0 = blockIdx.x * 64;
  const int j0 = blockIdx.y * 64;
  const int t = threadIdx.x, w = t >> 6, lane = t & 63;
  const int l16 = lane & 15, g4 = lane >> 4;
  const int cl = t >> 3, el = (t & 7) * 8;
  const int arow = t >> 2, aoff = (t & 3) * 8;
  f32x4 acc[4] = {};
  for (int k0 = 0; k0 < CO; k0 += 32) {
    const float* wp = Wout + (size_t)(k0 + cl) * CO + j0 + el;
    float4 b0 = *reinterpret_cast<const float4*>(wp);
    float4 b1 = *reinterpret_cast<const float4*>(wp + 4);
    f16x8 a8 = *reinterpret_cast<const f16x8*>(
        ao + ((size_t)b * NTOK + n0 + arow) * CO + k0 + aoff);
    Ws[el + 0][cl] = (f16)b0.x;  Ws[el + 1][cl] = (f16)b0.y;
    Ws[el + 2][cl] = (f16)b0.z;  Ws[el + 3][cl] = (f16)b0.w;
    Ws[el + 4][cl] = (f16)b1.x;  Ws[el + 5][cl] = (f16)b1.y;
    Ws[el + 6][cl] = (f16)b1.z;  Ws[el + 7][cl] = (f16)b1.w;
    *reinterpret_cast<f16x8*>(&Aos[arow][aoff]) = a8;
    __syncthreads();
    f16x8 wf = *reinterpret_cast<const f16x8*>(&Ws[w * 16 + l16][g4 * 8]);
#pragma unroll
    for (int nf = 0; nf < 4; ++nf) {
      f16x8 af = *reinterpret_cast<const f16x8*>(&Aos[nf * 16 + l16][g4 * 8]);
      acc[nf] = mfma16(wf, af, acc[nf]);
    }
    __syncthreads();
  }
#pragma unroll
  for (int nf = 0; nf < 4; ++nf) {
#pragma unroll
    for (int r = 0; r < 4; ++r) {
      const int j = j0 + w * 16 + g4 * 4 + r;
      const int n = n0 + nf * 16 + l16;
      out[((size_t)b * CO + j) * NTOK + n] = acc[nf][r] + bout[j];
    }
  }
}

extern "C" void kernel_launch(void* const* d_in, const int* in_sizes, int n_in,
                              void* d_out, int out_size, void* d_ws, size_t ws_size,
                              hipStream_t stream) {
  const float* x    = (const float*)d_in[0];
  const float* Wqkv = (const float*)d_in[1];
  const float* bqkv = (const float*)d_in[2];
  const float* Wout = (const float*)d_in[3];
  const float* bout = (const float*)d_in[4];
  float* out = (float*)d_out;

  f16* qbuf = (f16*)d_ws;
  const size_t seg = (size_t)2 * NH * NTOK * DH;   // 2,097,152 elements (4 MB)
  f16* kbuf = qbuf + seg;
  f16* vbuf = kbuf + seg;
  f16* ao   = vbuf + seg;

  qkv_kernel<<<dim3(NTOK / 64, C3 / 64, 2), 256, 0, stream>>>(x, Wqkv, bqkv, qbuf, kbuf, vbuf);
  attn_kernel<<<dim3(NTOK / 64, 16), 256, 0, stream>>>(qbuf, kbuf, vbuf, ao);
  proj_kernel<<<dim3(NTOK / 64, CO / 64, 2), 256, 0, stream>>>(ao, Wout, bout, out);
}

// Round 2
// 154.631 us; speedup vs baseline: 1.5002x; 1.5002x over previous
//
#include <hip/hip_runtime.h>

typedef _Float16 f16;
typedef _Float16 f16x4 __attribute__((ext_vector_type(4)));
typedef _Float16 f16x8 __attribute__((ext_vector_type(8)));
typedef float f32x4 __attribute__((ext_vector_type(4)));

#define NTOK 4096
#define CIN  256
#define C3   768
#define CO   256
#define NH   8
#define DH   32

__device__ __forceinline__ f32x4 mfma16(f16x8 a, f16x8 b, f32x4 c) {
  return __builtin_amdgcn_mfma_f32_16x16x32_f16(a, b, c, 0, 0, 0);
}

// ---------------------------------------------------------------------------
// Kernel 1: qkv = x^T @ W_qkv + b_qkv  (x is [B, C, N] channel-major)
// qbuf [bh][n][32] f16, PRE-SCALED by log2(e)/sqrt(32)  (softmax in log2 domain)
// kbuf [bh][n][32] f16
// vbuf [bh][d][n]  f16 (d-major)
// ---------------------------------------------------------------------------
__global__ __launch_bounds__(256) void qkv_kernel(
    const float* __restrict__ x, const float* __restrict__ Wqkv,
    const float* __restrict__ bqkv,
    f16* __restrict__ qbuf, f16* __restrict__ kbuf, f16* __restrict__ vbuf)
{
  __shared__ f16 As[64][40];
  __shared__ f16 Bs[64][40];
  const int b  = blockIdx.z;
  const int n0 = blockIdx.x * 64;
  const int j0 = blockIdx.y * 64;
  const int t  = threadIdx.x;
  const int w  = t >> 6;
  const int lane = t & 63;
  const int l16  = lane & 15;
  const int g4   = lane >> 4;
  const int cl = t >> 3;
  const int el = (t & 7) * 8;

  f32x4 acc[4] = {};
  for (int k0 = 0; k0 < CIN; k0 += 32) {
    const float* xp = x + ((size_t)b * CIN + (k0 + cl)) * NTOK + n0 + el;
    float4 a0 = *reinterpret_cast<const float4*>(xp);
    float4 a1 = *reinterpret_cast<const float4*>(xp + 4);
    const float* wp = Wqkv + (size_t)(k0 + cl) * C3 + j0 + el;
    float4 b0 = *reinterpret_cast<const float4*>(wp);
    float4 b1 = *reinterpret_cast<const float4*>(wp + 4);
    As[el + 0][cl] = (f16)a0.x;  As[el + 1][cl] = (f16)a0.y;
    As[el + 2][cl] = (f16)a0.z;  As[el + 3][cl] = (f16)a0.w;
    As[el + 4][cl] = (f16)a1.x;  As[el + 5][cl] = (f16)a1.y;
    As[el + 6][cl] = (f16)a1.z;  As[el + 7][cl] = (f16)a1.w;
    Bs[el + 0][cl] = (f16)b0.x;  Bs[el + 1][cl] = (f16)b0.y;
    Bs[el + 2][cl] = (f16)b0.z;  Bs[el + 3][cl] = (f16)b0.w;
    Bs[el + 4][cl] = (f16)b1.x;  Bs[el + 5][cl] = (f16)b1.y;
    Bs[el + 6][cl] = (f16)b1.z;  Bs[el + 7][cl] = (f16)b1.w;
    __syncthreads();
    f16x8 bf = *reinterpret_cast<const f16x8*>(&Bs[w * 16 + l16][g4 * 8]);
#pragma unroll
    for (int mf = 0; mf < 4; ++mf) {
      f16x8 af = *reinterpret_cast<const f16x8*>(&As[mf * 16 + l16][g4 * 8]);
      acc[mf] = mfma16(af, bf, acc[mf]);
    }
    __syncthreads();
  }
  const int j  = j0 + w * 16 + l16;
  const int s  = j >> 8;
  const int hh = (j >> 5) & 7;
  const int d  = j & 31;
  const float bias = bqkv[j];
  const float qscale = 0.25503472f;  // log2(e)/sqrt(32)
#pragma unroll
  for (int mf = 0; mf < 4; ++mf) {
#pragma unroll
    for (int r = 0; r < 4; ++r) {
      const int n = n0 + mf * 16 + g4 * 4 + r;
      const float v = acc[mf][r] + bias;
      if (s == 0) {
        qbuf[(((size_t)b * NH + hh) * NTOK + n) * DH + d] = (f16)(v * qscale);
      } else if (s == 1) {
        kbuf[(((size_t)b * NH + hh) * NTOK + n) * DH + d] = (f16)v;
      } else {
        vbuf[(((size_t)(b * NH + hh)) * DH + d) * NTOK + n] = (f16)v;
      }
    }
  }
}

// ---------------------------------------------------------------------------
// Kernel 2: flash attention, swapped-operand QK^T (S^T in registers).
// Block = 64 q-rows x one (b,h); 4 waves x 16 q-rows. KV tile = 64.
// S^T = mfma(A=K, B=Q): lane l16 = q, kv = nf*16 + g4*4 + r.
// P stays in registers; PV uses matching permuted k-map on V^T from LDS.
// ---------------------------------------------------------------------------
__global__ __launch_bounds__(256) void attn_kernel(
    const f16* __restrict__ qbuf, const f16* __restrict__ kbuf,
    const f16* __restrict__ vbuf, f16* __restrict__ ao)
{
  __shared__ f16 Vt[2][32][72];     // [buf][d][kv]
  const int bh = blockIdx.y;
  const int b = bh >> 3, h = bh & 7;
  const int q0 = blockIdx.x * 64;
  const int t = threadIdx.x, w = t >> 6, lane = t & 63;
  const int l16 = lane & 15, g4 = lane >> 4;
  const size_t kbase = (size_t)bh * NTOK * DH;

  f16x8 qfrag = *reinterpret_cast<const f16x8*>(
      qbuf + kbase + (size_t)(q0 + w * 16 + l16) * DH + g4 * 8);

  f32x4 oacc[2] = {};
  float mrun = -1e30f, lrun = 0.f;

  const int vd = t >> 3, vkoff = (t & 7) * 8;   // V stage: 32 rows x 64
  const f16* vsrc = vbuf + kbase + (size_t)vd * NTOK;

  // prologue: stage V tile 0, load K frags tile 0
  {
    f16x8 vv0 = *reinterpret_cast<const f16x8*>(vsrc + vkoff);
    *reinterpret_cast<f16x8*>(&Vt[0][vd][vkoff]) = vv0;
  }
  f16x8 kf[4];
#pragma unroll
  for (int nf = 0; nf < 4; ++nf)
    kf[nf] = *reinterpret_cast<const f16x8*>(
        kbuf + kbase + (size_t)(nf * 16 + l16) * DH + g4 * 8);
  __syncthreads();

#pragma unroll 2
  for (int tt = 0; tt < 64; ++tt) {
    const int cur = tt & 1;
    const int kvn = ((tt + 1) & 63) * 64;   // next tile (wraps; tail load unused)

    // prefetch next K frags + V stage-load (issued early, consumed late)
    f16x8 kn[4];
#pragma unroll
    for (int nf = 0; nf < 4; ++nf)
      kn[nf] = *reinterpret_cast<const f16x8*>(
          kbuf + kbase + (size_t)(kvn + nf * 16 + l16) * DH + g4 * 8);
    f16x8 vv = *reinterpret_cast<const f16x8*>(vsrc + kvn + vkoff);

    // S^T = K Q^T : col=l16=q, row = kv (per lane: kv = nf*16 + g4*4 + r)
    f32x4 sv[4];
#pragma unroll
    for (int nf = 0; nf < 4; ++nf) {
      f32x4 z = {};
      sv[nf] = mfma16(kf[nf], qfrag, z);
    }

    // row max (16 in-register + 2 shfl)
    float mx = fmaxf(fmaxf(fmaxf(sv[0][0], sv[0][1]), fmaxf(sv[0][2], sv[0][3])),
                     fmaxf(fmaxf(sv[1][0], sv[1][1]), fmaxf(sv[1][2], sv[1][3])));
    mx = fmaxf(mx, fmaxf(fmaxf(fmaxf(sv[2][0], sv[2][1]), fmaxf(sv[2][2], sv[2][3])),
                         fmaxf(fmaxf(sv[3][0], sv[3][1]), fmaxf(sv[3][2], sv[3][3]))));
    mx = fmaxf(mx, __shfl_xor(mx, 16));
    mx = fmaxf(mx, __shfl_xor(mx, 32));

    // defer-max rescale (log2 domain, P bounded by 2^8)
    if (!__all(mx - mrun <= 8.0f)) {
      const float mnew = fmaxf(mrun, mx);
      const float alpha = exp2f(mrun - mnew);
      lrun *= alpha;
      oacc[0] *= alpha;
      oacc[1] *= alpha;
      mrun = mnew;
    }

    // P = exp2(S - m), packed directly as PV B-fragments
    float p[4][4];
    float lsum = 0.f;
#pragma unroll
    for (int nf = 0; nf < 4; ++nf)
#pragma unroll
      for (int r = 0; r < 4; ++r) {
        const float e = exp2f(sv[nf][r] - mrun);
        p[nf][r] = e;
        lsum += e;
      }
    lsum += __shfl_xor(lsum, 16);
    lsum += __shfl_xor(lsum, 32);
    lrun += lsum;

    f16x8 pb0, pb1;
#pragma unroll
    for (int r = 0; r < 4; ++r) {
      pb0[r]     = (f16)p[0][r];
      pb0[r + 4] = (f16)p[1][r];
      pb1[r]     = (f16)p[2][r];
      pb1[r + 4] = (f16)p[3][r];
    }

    // O^T += V^T P^T, V read with the SAME permuted k-map as pb
#pragma unroll
    for (int df = 0; df < 2; ++df) {
      const f16* vr = &Vt[cur][16 * df + l16][0];
      f16x4 a0 = *reinterpret_cast<const f16x4*>(vr + g4 * 4);
      f16x4 a1 = *reinterpret_cast<const f16x4*>(vr + 16 + g4 * 4);
      f16x8 va0 = __builtin_shufflevector(a0, a1, 0, 1, 2, 3, 4, 5, 6, 7);
      oacc[df] = mfma16(va0, pb0, oacc[df]);
      f16x4 b0 = *reinterpret_cast<const f16x4*>(vr + 32 + g4 * 4);
      f16x4 b1 = *reinterpret_cast<const f16x4*>(vr + 48 + g4 * 4);
      f16x8 va1 = __builtin_shufflevector(b0, b1, 0, 1, 2, 3, 4, 5, 6, 7);
      oacc[df] = mfma16(va1, pb1, oacc[df]);
    }

    // stage next V tile into the other buffer; one barrier per tile
    *reinterpret_cast<f16x8*>(&Vt[cur ^ 1][vd][vkoff]) = vv;
    __syncthreads();

#pragma unroll
    for (int nf = 0; nf < 4; ++nf) kf[nf] = kn[nf];
  }

  // epilogue: O[q=l16][d = 16*df + g4*4 + r] / lrun
  const float inv = 1.0f / lrun;
  const size_t orow = ((size_t)b * NTOK + q0 + w * 16 + l16) * CO + h * DH;
#pragma unroll
  for (int df = 0; df < 2; ++df) {
    f16x4 st;
#pragma unroll
    for (int r = 0; r < 4; ++r) st[r] = (f16)(oacc[df][r] * inv);
    *reinterpret_cast<f16x4*>((f16*)ao + orow + 16 * df + g4 * 4) = st;
  }
}

// ---------------------------------------------------------------------------
// Kernel 3: out[b][j][n] = sum_c ao[b][n][c] * Wout[c][j] + bout[j]
// ---------------------------------------------------------------------------
__global__ __launch_bounds__(256) void proj_kernel(
    const f16* __restrict__ ao, const float* __restrict__ Wout,
    const float* __restrict__ bout, float* __restrict__ out)
{
  __shared__ f16 Ws[64][40];
  __shared__ f16 Aos[64][40];
  const int b  = blockIdx.z;
  const int n0 = blockIdx.x * 64;
  const int j0 = blockIdx.y * 64;
  const int t = threadIdx.x, w = t >> 6, lane = t & 63;
  const int l16 = lane & 15, g4 = lane >> 4;
  const int cl = t >> 3, el = (t & 7) * 8;
  const int arow = t >> 2, aoff = (t & 3) * 8;
  f32x4 acc[4] = {};
  for (int k0 = 0; k0 < CO; k0 += 32) {
    const float* wp = Wout + (size_t)(k0 + cl) * CO + j0 + el;
    float4 b0 = *reinterpret_cast<const float4*>(wp);
    float4 b1 = *reinterpret_cast<const float4*>(wp + 4);
    f16x8 a8 = *reinterpret_cast<const f16x8*>(
        ao + ((size_t)b * NTOK + n0 + arow) * CO + k0 + aoff);
    Ws[el + 0][cl] = (f16)b0.x;  Ws[el + 1][cl] = (f16)b0.y;
    Ws[el + 2][cl] = (f16)b0.z;  Ws[el + 3][cl] = (f16)b0.w;
    Ws[el + 4][cl] = (f16)b1.x;  Ws[el + 5][cl] = (f16)b1.y;
    Ws[el + 6][cl] = (f16)b1.z;  Ws[el + 7][cl] = (f16)b1.w;
    *reinterpret_cast<f16x8*>(&Aos[arow][aoff]) = a8;
    __syncthreads();
    f16x8 wf = *reinterpret_cast<const f16x8*>(&Ws[w * 16 + l16][g4 * 8]);
#pragma unroll
    for (int nf = 0; nf < 4; ++nf) {
      f16x8 af = *reinterpret_cast<const f16x8*>(&Aos[nf * 16 + l16][g4 * 8]);
      acc[nf] = mfma16(wf, af, acc[nf]);
    }
    __syncthreads();
  }
#pragma unroll
  for (int nf = 0; nf < 4; ++nf) {
#pragma unroll
    for (int r = 0; r < 4; ++r) {
      const int j = j0 + w * 16 + g4 * 4 + r;
      const int n = n0 + nf * 16 + l16;
      out[((size_t)b * CO + j) * NTOK + n] = acc[nf][r] + bout[j];
    }
  }
}

extern "C" void kernel_launch(void* const* d_in, const int* in_sizes, int n_in,
                              void* d_out, int out_size, void* d_ws, size_t ws_size,
                              hipStream_t stream) {
  const float* x    = (const float*)d_in[0];
  const float* Wqkv = (const float*)d_in[1];
  const float* bqkv = (const float*)d_in[2];
  const float* Wout = (const float*)d_in[3];
  const float* bout = (const float*)d_in[4];
  float* out = (float*)d_out;

  f16* qbuf = (f16*)d_ws;
  const size_t seg = (size_t)2 * NH * NTOK * DH;
  f16* kbuf = qbuf + seg;
  f16* vbuf = kbuf + seg;
  f16* ao   = vbuf + seg;

  qkv_kernel<<<dim3(NTOK / 64, C3 / 64, 2), 256, 0, stream>>>(x, Wqkv, bqkv, qbuf, kbuf, vbuf);
  attn_kernel<<<dim3(NTOK / 64, 16), 256, 0, stream>>>(qbuf, kbuf, vbuf, ao);
  proj_kernel<<<dim3(NTOK / 64, CO / 64, 2), 256, 0, stream>>>(ao, Wout, bout, out);
}